// Round 10
// baseline (574.807 us; speedup 1.0000x reference)
//
#include <hip/hip_runtime.h>
#include <hip/hip_bf16.h>
#include <math.h>

#define BB 8
#define CC 128
#define NTOK 2304   // 48*48
#define KTOP 1843   // int(2304*0.8)

typedef unsigned short u16;
typedef unsigned int   u32;
typedef __attribute__((ext_vector_type(8))) short short8;
typedef __attribute__((ext_vector_type(4))) float f32x4;

static __device__ __forceinline__ float bf2f(u16 u) {
    return __uint_as_float(((u32)u) << 16);
}
static __device__ __forceinline__ u16 f2bf(float f) {
    u32 x = __float_as_uint(f);
    return (u16)((x + 0x7fffu + ((x >> 16) & 1u)) >> 16);  // RNE
}
// monotone 16-bit key <-> bf16 value
static __device__ __forceinline__ float key2val(int k) {
    u32 raw = (k & 0x8000) ? (u32)(k ^ 0x8000) : ((~(u32)k) & 0xFFFFu);
    return __uint_as_float(raw << 16);
}

// ---------------- Kernel 1: QKV projections (bf16 outputs) ----------------
// Q,K: [B,N,C] bf16 (Q pre-scaled by 1/sqrt(C)); V: [B,C,N] bf16 (transposed).
__global__ __launch_bounds__(256) void qkv_kernel(
    const float* __restrict__ x,
    const float* __restrict__ Wq, const float* __restrict__ bq,
    const float* __restrict__ Wk, const float* __restrict__ bk,
    const float* __restrict__ Wv, const float* __restrict__ bv,
    u16* __restrict__ q_ws, u16* __restrict__ k_ws, u16* __restrict__ v_ws)
{
    __shared__ float t_lds[128 * 68];   // [c][r]
    __shared__ u16 st[64 * 128];        // transpose staging for q/k stores
    int blk = blockIdx.x;
    int b  = blk / 36;
    int n0 = (blk % 36) * 64;
    int tid = threadIdx.x;
    const float* xb = x + (size_t)(b * NTOK + n0) * CC;
    #pragma unroll
    for (int k = 0; k < 32; ++k) {
        int idx = k * 256 + tid;
        t_lds[(idx & 127) * 68 + (idx >> 7)] = xb[idx];
    }
    __syncthreads();
    int o  = tid & 127;
    int rh = tid >> 7;
    const float* Ws[3] = {Wq, Wk, Wv};
    const float* bs[3] = {bq, bk, bv};
    for (int mat = 0; mat < 3; ++mat) {
        const float* W = Ws[mat];
        float acc[32];
        #pragma unroll
        for (int j = 0; j < 32; ++j) acc[j] = 0.f;
        for (int c = 0; c < 128; ++c) {
            float w = W[o * 128 + c];
            const float4* t4p = (const float4*)&t_lds[c * 68 + rh * 32];
            #pragma unroll
            for (int j4 = 0; j4 < 8; ++j4) {
                float4 t4 = t4p[j4];
                acc[j4*4+0] += t4.x * w;
                acc[j4*4+1] += t4.y * w;
                acc[j4*4+2] += t4.z * w;
                acc[j4*4+3] += t4.w * w;
            }
        }
        float bias = bs[mat][o];
        if (mat == 2) {
            ushort4* vp4 = (ushort4*)(v_ws + (size_t)(b * CC + o) * NTOK + n0 + rh * 32);
            #pragma unroll
            for (int j8 = 0; j8 < 8; ++j8) {
                ushort4 s;
                s.x = f2bf(acc[j8*4+0] + bias); s.y = f2bf(acc[j8*4+1] + bias);
                s.z = f2bf(acc[j8*4+2] + bias); s.w = f2bf(acc[j8*4+3] + bias);
                vp4[j8] = s;
            }
        } else {
            float sc = (mat == 0) ? 0.08838834764831845f : 1.0f;  // fold 1/sqrt(C) into Q
            #pragma unroll
            for (int j = 0; j < 32; ++j)
                st[(rh * 32 + j) * 128 + o] = f2bf((acc[j] + bias) * sc);
            __syncthreads();
            u16* gp = (mat == 0 ? q_ws : k_ws) + (size_t)(b * NTOK + n0) * CC;
            const ushort4* s4 = (const ushort4*)st;
            ushort4* g4 = (ushort4*)gp;
            for (int k = tid; k < 2048; k += 256) g4[k] = s4[k];
            __syncthreads();
        }
    }
}

// ---------------- Kernel 2a: QK^T GEMM -> monotone u16 keys [B][N][N] ------
// Block: 64 q-rows x 64 m-cols, 4 waves (wave = 16q x 64m), no LDS.
__global__ __launch_bounds__(256) void qk_kernel(
    const u16* __restrict__ q_ws, const u16* __restrict__ k_ws,
    u16* __restrict__ sc)
{
    int tid = threadIdx.x;
    int lane = tid & 63, wid = tid >> 6;
    int blk = blockIdx.x;
    int b = blk & 7;                // one batch per XCD (Q,K L2-resident)
    int t = blk >> 3;               // 0..1295
    int qt = t % 36, mt = t / 36;
    int q0 = qt * 64 + wid * 16;
    int m0 = mt * 64;
    int fr = lane & 15, fg = lane >> 4;

    const u16* qb = q_ws + (size_t)(b * NTOK + q0 + fr) * CC + fg * 8;
    short8 qa[4];
    #pragma unroll
    for (int kc = 0; kc < 4; ++kc) qa[kc] = *(const short8*)(qb + kc * 32);

    const u16* kb = k_ws + (size_t)(b * NTOK + m0 + fr) * CC + fg * 8;
    f32x4 acc[4];
    #pragma unroll
    for (int i = 0; i < 4; ++i) acc[i] = (f32x4){0.f, 0.f, 0.f, 0.f};
    #pragma unroll
    for (int mt2 = 0; mt2 < 4; ++mt2) {
        const u16* kp = kb + (size_t)(mt2 * 16) * CC;
        #pragma unroll
        for (int kc = 0; kc < 4; ++kc) {
            short8 kf = *(const short8*)(kp + kc * 32);
            acc[mt2] = __builtin_amdgcn_mfma_f32_16x16x32_bf16(qa[kc], kf, acc[mt2], 0, 0, 0);
        }
    }
    #pragma unroll
    for (int mt2 = 0; mt2 < 4; ++mt2) {
        #pragma unroll
        for (int r = 0; r < 4; ++r) {
            int row = q0 + fg * 4 + r;
            int col = m0 + mt2 * 16 + fr;
            u16 raw = f2bf(acc[mt2][r]);
            u16 key = (raw & 0x8000u) ? (u16)~raw : (u16)(raw | 0x8000u);
            sc[((size_t)b * NTOK + row) * NTOK + col] = key;
        }
    }
}

// ---------------- Kernel 2b: exact top-k + masked softmax (writes P) -------
// Block = 4 waves x 2 fused rows = 8 rows; keys in registers; no LDS/barriers.
// Writes P (bf16) in place over keys; params[row].z = 1/sum for pv epilogue.
__global__ __launch_bounds__(256) void topk_kernel(
    u16* __restrict__ sc, float4* __restrict__ params)
{
    int tid = threadIdx.x;
    int lane = tid & 63, wid = tid >> 6;
    size_t rg0 = (size_t)blockIdx.x * 8 + wid * 2;
    u16* s0 = sc + rg0 * NTOK;
    u16* s1 = s0 + NTOK;

    int keys0[36], keys1[36];
    int kmax0 = 0, kmax1 = 0;
    #pragma unroll
    for (int j = 0; j < 9; ++j) {
        ushort4 a = *(const ushort4*)(s0 + j * 256 + lane * 4);
        ushort4 c = *(const ushort4*)(s1 + j * 256 + lane * 4);
        keys0[j*4+0] = a.x; keys0[j*4+1] = a.y; keys0[j*4+2] = a.z; keys0[j*4+3] = a.w;
        keys1[j*4+0] = c.x; keys1[j*4+1] = c.y; keys1[j*4+2] = c.z; keys1[j*4+3] = c.w;
        kmax0 = max(kmax0, max(max((int)a.x, (int)a.y), max((int)a.z, (int)a.w)));
        kmax1 = max(kmax1, max(max((int)c.x, (int)c.y), max((int)c.z, (int)c.w)));
    }
    #pragma unroll
    for (int off = 32; off; off >>= 1) {
        kmax0 = max(kmax0, __shfl_xor(kmax0, off, 64));
        kmax1 = max(kmax1, __shfl_xor(kmax1, off, 64));
    }
    u32 res0 = 0, res1 = 0;
    for (int bit = 15; bit >= 0; --bit) {
        int cand0 = (int)(res0 | (1u << bit));
        int cand1 = (int)(res1 | (1u << bit));
        int c0 = 0, c1 = 0;
        #pragma unroll
        for (int j = 0; j < 36; ++j) {
            c0 += (keys0[j] >= cand0) ? 1 : 0;
            c1 += (keys1[j] >= cand1) ? 1 : 0;
        }
        #pragma unroll
        for (int off = 32; off; off >>= 1) {
            c0 += __shfl_xor(c0, off, 64);
            c1 += __shfl_xor(c1, off, 64);
        }
        if (c0 >= KTOP) res0 = (u32)cand0;
        if (c1 >= KTOP) res1 = (u32)cand1;
    }
    float vmax0 = key2val(kmax0), vmax1 = key2val(kmax1);
    float sum0 = 0.f, sum1 = 0.f;
    #pragma unroll
    for (int j = 0; j < 9; ++j) {
        ushort4 w0, w1;
        float e;
        e = ((u32)keys0[j*4+0] >= res0) ? __expf(key2val(keys0[j*4+0]) - vmax0) : 0.f; sum0 += e; w0.x = f2bf(e);
        e = ((u32)keys0[j*4+1] >= res0) ? __expf(key2val(keys0[j*4+1]) - vmax0) : 0.f; sum0 += e; w0.y = f2bf(e);
        e = ((u32)keys0[j*4+2] >= res0) ? __expf(key2val(keys0[j*4+2]) - vmax0) : 0.f; sum0 += e; w0.z = f2bf(e);
        e = ((u32)keys0[j*4+3] >= res0) ? __expf(key2val(keys0[j*4+3]) - vmax0) : 0.f; sum0 += e; w0.w = f2bf(e);
        e = ((u32)keys1[j*4+0] >= res1) ? __expf(key2val(keys1[j*4+0]) - vmax1) : 0.f; sum1 += e; w1.x = f2bf(e);
        e = ((u32)keys1[j*4+1] >= res1) ? __expf(key2val(keys1[j*4+1]) - vmax1) : 0.f; sum1 += e; w1.y = f2bf(e);
        e = ((u32)keys1[j*4+2] >= res1) ? __expf(key2val(keys1[j*4+2]) - vmax1) : 0.f; sum1 += e; w1.z = f2bf(e);
        e = ((u32)keys1[j*4+3] >= res1) ? __expf(key2val(keys1[j*4+3]) - vmax1) : 0.f; sum1 += e; w1.w = f2bf(e);
        *(ushort4*)(s0 + j * 256 + lane * 4) = w0;
        *(ushort4*)(s1 + j * 256 + lane * 4) = w1;
    }
    #pragma unroll
    for (int off = 32; off; off >>= 1) {
        sum0 += __shfl_xor(sum0, off, 64);
        sum1 += __shfl_xor(sum1, off, 64);
    }
    if (lane == 0) {
        params[rg0]     = make_float4(0.f, vmax0, 1.f / sum0, 0.f);
        params[rg0 + 1] = make_float4(0.f, vmax1, 1.f / sum1, 0.f);
    }
}

// ---------------- Kernel 2c: PV GEMM (P read directly, no VALU exp) --------
// Block = 4 waves x 16 rows; wave w owns c-cols [w*32, w*32+32), full m-range.
__global__ __launch_bounds__(256) void pv_kernel(
    const u16* __restrict__ sc, const u16* __restrict__ v_ws,
    const float4* __restrict__ params, float* __restrict__ xs_ws)
{
    int tid = threadIdx.x;
    int lane = tid & 63, wid = tid >> 6;
    int blk = blockIdx.x;
    int b = blk & 7;                 // one batch per XCD (V L2-resident)
    int rt = blk >> 3;               // 0..143
    int r0 = rt * 16;
    int c0 = wid * 32;
    int fr = lane & 15, fg = lane >> 4;
    int row = r0 + fr;

    const u16* pb = sc + ((size_t)b * NTOK + row) * NTOK + fg * 8;
    const u16* vb = v_ws + ((size_t)b * CC + c0 + fr) * NTOK + fg * 8;

    f32x4 acc0 = {0.f, 0.f, 0.f, 0.f};
    f32x4 acc1 = {0.f, 0.f, 0.f, 0.f};

    #pragma unroll 4
    for (int ch = 0; ch < 72; ++ch) {
        int m0 = ch * 32;
        short8 pa = *(const short8*)(pb + m0);
        short8 vf0 = *(const short8*)(vb + m0);
        short8 vf1 = *(const short8*)(vb + (size_t)16 * NTOK + m0);
        acc0 = __builtin_amdgcn_mfma_f32_16x16x32_bf16(pa, vf0, acc0, 0, 0, 0);
        acc1 = __builtin_amdgcn_mfma_f32_16x16x32_bf16(pa, vf1, acc1, 0, 0, 0);
    }
    #pragma unroll
    for (int r = 0; r < 4; ++r) {
        int orow = r0 + fg * 4 + r;
        float inv = params[(size_t)b * NTOK + orow].z;
        float* op = xs_ws + ((size_t)b * NTOK + orow) * CC + c0;
        op[fr]      = acc0[r] * inv;
        op[16 + fr] = acc1[r] * inv;
    }
}

// ---------------- Kernel 3: gate conv + sigmoid ----------------------------
__global__ __launch_bounds__(256) void gate_kernel(
    const float* __restrict__ xs_ws, const float* __restrict__ gw,
    const float* __restrict__ gb, float* __restrict__ imp_ws)
{
    __shared__ float gsum[256];
    int blk = blockIdx.x;
    int b  = blk & 7;
    int p0 = (blk >> 3) * 64;
    int tid = threadIdx.x;
    int pl = tid & 63, cq = tid >> 6;
    int p = p0 + pl;
    int h = p / 48, w = p % 48;
    float acc = 0.f;
    const float* xb = xs_ws + (size_t)b * CC * NTOK;
    for (int i = cq * 32; i < cq * 32 + 32; ++i) {
        const float* plane = xb + (size_t)i * NTOK;
        const float* wv = gw + i * 9;
        #pragma unroll
        for (int kh = 0; kh < 3; ++kh) {
            int hh = h + kh - 1;
            if ((unsigned)hh >= 48u) continue;
            #pragma unroll
            for (int kw = 0; kw < 3; ++kw) {
                int ww = w + kw - 1;
                if ((unsigned)ww >= 48u) continue;
                acc += plane[hh * 48 + ww] * wv[kh * 3 + kw];
            }
        }
    }
    gsum[cq * 64 + pl] = acc;
    __syncthreads();
    if (tid < 64) {
        float s = gsum[tid] + gsum[64 + tid] + gsum[128 + tid] + gsum[192 + tid] + gb[0];
        imp_ws[b * NTOK + p0 + tid] = 1.f / (1.f + __expf(-s));
    }
}

// ---------------- Kernel 3b: weight transform -> wb[tap][o][c] bf16 --------
__global__ __launch_bounds__(256) void wtrans_kernel(
    const float* __restrict__ rw, const float* __restrict__ cw,
    u16* __restrict__ wb_ref, u16* __restrict__ wb_cov)
{
    int idx = blockIdx.x * 256 + threadIdx.x;     // 0..294911
    int which = idx >= 147456;
    int rem = which ? idx - 147456 : idx;
    int tap = rem >> 14;                           // /16384
    int rest = rem & 16383;
    int o = rest >> 7, c = rest & 127;
    const float* src = which ? cw : rw;
    u16* dst = which ? wb_cov : wb_ref;
    dst[rem] = f2bf(src[(o * 128 + c) * 9 + tap]);
}

// ---------------- Kernel 3c: transpose to pixel-major + residual buffer ----
__global__ __launch_bounds__(256) void tpos_kernel(
    const float* __restrict__ xs_ws, const float* __restrict__ prev,
    const float* __restrict__ imp_ws,
    u16* __restrict__ xt_g, float* __restrict__ rbuf)
{
    __shared__ float tx[128 * 65];
    __shared__ float tp[128 * 65];
    int blk = blockIdx.x;
    int b  = blk & 7;
    int p0 = (blk >> 3) * 64;
    int tid = threadIdx.x;
    const float* xsb = xs_ws + (size_t)b * CC * NTOK + p0;
    const float* pvb = prev  + (size_t)b * CC * NTOK + p0;
    #pragma unroll
    for (int it = 0; it < 32; ++it) {
        int idx = it * 256 + tid;
        int i = idx >> 6, pp = idx & 63;
        tx[i * 65 + pp] = xsb[(size_t)i * NTOK + pp];
        tp[i * 65 + pp] = pvb[(size_t)i * NTOK + pp];
    }
    __syncthreads();
    int pl = tid & 63, cq = tid >> 6;
    float impv = imp_ws[b * NTOK + p0 + pl];
    size_t obase = ((size_t)b * NTOK + p0 + pl) * CC + cq * 32;
    u16* gout = xt_g + obase;
    float* rout = rbuf + obase;
    #pragma unroll
    for (int j4 = 0; j4 < 8; ++j4) {
        float4 rv; ushort4 gv;
        float v0 = tx[(cq * 32 + j4 * 4 + 0) * 65 + pl];
        float v1 = tx[(cq * 32 + j4 * 4 + 1) * 65 + pl];
        float v2 = tx[(cq * 32 + j4 * 4 + 2) * 65 + pl];
        float v3 = tx[(cq * 32 + j4 * 4 + 3) * 65 + pl];
        float q0 = tp[(cq * 32 + j4 * 4 + 0) * 65 + pl];
        float q1 = tp[(cq * 32 + j4 * 4 + 1) * 65 + pl];
        float q2 = tp[(cq * 32 + j4 * 4 + 2) * 65 + pl];
        float q3 = tp[(cq * 32 + j4 * 4 + 3) * 65 + pl];
        rv.x = v0 + 0.5f * q0; rv.y = v1 + 0.5f * q1;
        rv.z = v2 + 0.5f * q2; rv.w = v3 + 0.5f * q3;
        gv.x = f2bf(v0 * impv); gv.y = f2bf(v1 * impv);
        gv.z = f2bf(v2 * impv); gv.w = f2bf(v3 * impv);
        *(float4*)(rout + j4 * 4) = rv;
        *(ushort4*)(gout + j4 * 4) = gv;
    }
}

// ---------------- Kernel 4: refinement conv as implicit MFMA GEMM ----------
__global__ __launch_bounds__(256) void refgemm_kernel(
    const u16* __restrict__ xt_g, const u16* __restrict__ wb_ref,
    const float* __restrict__ rbuf, const float* __restrict__ rb,
    u16* __restrict__ xt2)
{
    __shared__ u16 slab[144 * 128];   // XOR-swizzled shifted input slab
    int tid = threadIdx.x;
    int lane = tid & 63, wid = tid >> 6;
    int blk = blockIdx.x;
    int b  = blk & 7;
    int st = (blk >> 3) & 15;
    int oh = blk >> 7;
    int h0 = st * 3;
    int p0g = st * 144;
    int fr = lane & 15, fg = lane >> 4;
    int o0 = oh * 64 + wid * 16;
    const u16* xb = xt_g + (size_t)b * NTOK * CC;

    f32x4 acc[9];
    #pragma unroll
    for (int pt = 0; pt < 9; ++pt) acc[pt] = (f32x4){0.f, 0.f, 0.f, 0.f};

    for (int tap = 0; tap < 9; ++tap) {
        int dh = tap / 3 - 1, dw = tap % 3 - 1;
        __syncthreads();
        #pragma unroll
        for (int it = 0; it < 9; ++it) {
            int idx = it * 256 + tid;          // 0..2303
            int pr = idx >> 4, cv = idx & 15;
            int r = pr >= 96 ? 2 : (pr >= 48 ? 1 : 0);
            int w = pr - r * 48;
            int sh = h0 + r + dh, sw = w + dw;
            short8 val = (short8){0,0,0,0,0,0,0,0};
            if ((unsigned)sh < 48u && (unsigned)sw < 48u)
                val = *(const short8*)(xb + (size_t)(sh * 48 + sw) * CC + cv * 8);
            *(short8*)(slab + pr * 128 + ((cv ^ (pr & 7)) * 8)) = val;
        }
        __syncthreads();
        #pragma unroll
        for (int kc = 0; kc < 4; ++kc) {
            short8 bfr = *(const short8*)(wb_ref + tap * 16384 + (o0 + fr) * 128 + kc * 32 + fg * 8);
            #pragma unroll
            for (int pt = 0; pt < 9; ++pt) {
                int prr = pt * 16 + fr;
                short8 pa = *(const short8*)(slab + prr * 128 + (((kc * 4 + fg) ^ (prr & 7)) * 8));
                acc[pt] = __builtin_amdgcn_mfma_f32_16x16x32_bf16(pa, bfr, acc[pt], 0, 0, 0);
            }
        }
    }
    int o = o0 + fr;
    float bias = rb[o];
    #pragma unroll
    for (int pt = 0; pt < 9; ++pt) {
        #pragma unroll
        for (int r = 0; r < 4; ++r) {
            int p = p0g + pt * 16 + fg * 4 + r;
            size_t off = ((size_t)b * NTOK + p) * CC + o;
            float v = acc[pt][r] + bias + rbuf[off];
            xt2[off] = f2bf(v);
        }
    }
}

// ---------------- Kernel 5: coverage conv (dil 2) as implicit MFMA GEMM ----
__global__ __launch_bounds__(256) void covgemm_kernel(
    const u16* __restrict__ xt2, const u16* __restrict__ wb_cov,
    const float* __restrict__ cb, float* __restrict__ out)
{
    __shared__ u16 slab[144 * 128];
    __shared__ float ldsout[4 * 16 * 145];   // per-wave [o][p] staging, padded
    int tid = threadIdx.x;
    int lane = tid & 63, wid = tid >> 6;
    int blk = blockIdx.x;
    int b  = blk & 7;
    int st = (blk >> 3) & 15;
    int oh = blk >> 7;
    int h0 = st * 3;
    int p0g = st * 144;
    int fr = lane & 15, fg = lane >> 4;
    int o0 = oh * 64 + wid * 16;
    const u16* xb = xt2 + (size_t)b * NTOK * CC;

    f32x4 acc[9];
    #pragma unroll
    for (int pt = 0; pt < 9; ++pt) acc[pt] = (f32x4){0.f, 0.f, 0.f, 0.f};

    for (int tap = 0; tap < 9; ++tap) {
        int dh = (tap / 3 - 1) * 2, dw = (tap % 3 - 1) * 2;
        __syncthreads();
        #pragma unroll
        for (int it = 0; it < 9; ++it) {
            int idx = it * 256 + tid;
            int pr = idx >> 4, cv = idx & 15;
            int r = pr >= 96 ? 2 : (pr >= 48 ? 1 : 0);
            int w = pr - r * 48;
            int sh = h0 + r + dh, sw = w + dw;
            short8 val = (short8){0,0,0,0,0,0,0,0};
            if ((unsigned)sh < 48u && (unsigned)sw < 48u)
                val = *(const short8*)(xb + (size_t)(sh * 48 + sw) * CC + cv * 8);
            *(short8*)(slab + pr * 128 + ((cv ^ (pr & 7)) * 8)) = val;
        }
        __syncthreads();
        #pragma unroll
        for (int kc = 0; kc < 4; ++kc) {
            short8 bfr = *(const short8*)(wb_cov + tap * 16384 + (o0 + fr) * 128 + kc * 32 + fg * 8);
            #pragma unroll
            for (int pt = 0; pt < 9; ++pt) {
                int prr = pt * 16 + fr;
                short8 pa = *(const short8*)(slab + prr * 128 + (((kc * 4 + fg) ^ (prr & 7)) * 8));
                acc[pt] = __builtin_amdgcn_mfma_f32_16x16x32_bf16(pa, bfr, acc[pt], 0, 0, 0);
            }
        }
    }
    float bias = cb[o0 + fr];
    float* lo = ldsout + wid * (16 * 145);
    #pragma unroll
    for (int pt = 0; pt < 9; ++pt) {
        #pragma unroll
        for (int r = 0; r < 4; ++r) {
            int pl = pt * 16 + fg * 4 + r;
            lo[fr * 145 + pl] = acc[pt][r] + bias;
        }
    }
    __syncthreads();
    float* ob = out + ((size_t)b * CC + o0) * NTOK + p0g;
    #pragma unroll
    for (int j = 0; j < 36; ++j) {
        int idx = j * 64 + lane;         // 0..2303
        int o_r = idx / 144;
        int p_r = idx - o_r * 144;
        ob[(size_t)o_r * NTOK + p_r] = lo[o_r * 145 + p_r];
    }
}

extern "C" void kernel_launch(void* const* d_in, const int* in_sizes, int n_in,
                              void* d_out, int out_size, void* d_ws, size_t ws_size,
                              hipStream_t stream)
{
    const float* x    = (const float*)d_in[0];
    const float* prev = (const float*)d_in[1];
    const float* Wq   = (const float*)d_in[2];
    const float* bq   = (const float*)d_in[3];
    const float* Wk   = (const float*)d_in[4];
    const float* bk   = (const float*)d_in[5];
    const float* Wv   = (const float*)d_in[6];
    const float* bv   = (const float*)d_in[7];
    const float* rw   = (const float*)d_in[8];
    const float* rb   = (const float*)d_in[9];
    const float* gw   = (const float*)d_in[10];
    const float* gb   = (const float*)d_in[11];
    const float* cw   = (const float*)d_in[12];
    const float* cb   = (const float*)d_in[13];
    float* out = (float*)d_out;
    char* ws = (char*)d_ws;

    const size_t SZ  = (size_t)BB * NTOK * CC;            // 2359296 elements
    const size_t BSZ = SZ * 2;                            // bf16 bytes
    const size_t FSZ = SZ * 4;                            // fp32 bytes
    const size_t SCB = (size_t)BB * NTOK * NTOK * 2;      // 84.9 MB key/P buffer
    const size_t PRB = (size_t)BB * NTOK * 16;            // params float4/row
    const size_t RIB = (size_t)BB * NTOK * 4;

    size_t off = 0;
    u16*    q_ws   = (u16*)(ws + off);    off += BSZ;
    u16*    k_ws   = (u16*)(ws + off);    off += BSZ;
    u16*    v_ws   = (u16*)(ws + off);    off += BSZ;
    u16*    sc_ws  = (u16*)(ws + off);    off += SCB;
    float4* prm_ws = (float4*)(ws + off); off += PRB;
    float*  xs_ws  = (float*)(ws + off);  off += FSZ;
    float*  imp_ws = (float*)(ws + off);  off += RIB;
    u16*    xt_g   = (u16*)(ws + off);    off += BSZ;
    float*  rbuf   = (float*)(ws + off);  off += FSZ;
    u16*    xt2    = (u16*)(ws + off);    off += BSZ;
    u16*    wb_ref = (u16*)(ws + off);    off += 294912;
    u16*    wb_cov = (u16*)(ws + off);    off += 294912;
    // total ~124 MB

    qkv_kernel<<<dim3(288), dim3(256), 0, stream>>>(x, Wq, bq, Wk, bk, Wv, bv,
                                                    q_ws, k_ws, v_ws);
    qk_kernel<<<dim3(10368), dim3(256), 0, stream>>>(q_ws, k_ws, sc_ws);
    topk_kernel<<<dim3(2304), dim3(256), 0, stream>>>(sc_ws, prm_ws);
    pv_kernel<<<dim3(1152), dim3(256), 0, stream>>>(sc_ws, v_ws, prm_ws, xs_ws);
    gate_kernel<<<dim3(288), dim3(256), 0, stream>>>(xs_ws, gw, gb, imp_ws);
    wtrans_kernel<<<dim3(1152), dim3(256), 0, stream>>>(rw, cw, wb_ref, wb_cov);
    tpos_kernel<<<dim3(288), dim3(256), 0, stream>>>(xs_ws, prev, imp_ws, xt_g, rbuf);
    refgemm_kernel<<<dim3(256), dim3(256), 0, stream>>>(xt_g, wb_ref, rbuf, rb, xt2);
    covgemm_kernel<<<dim3(256), dim3(256), 0, stream>>>(xt2, wb_cov, cb, out);
}

// Round 12
// 543.228 us; speedup vs baseline: 1.0581x; 1.0581x over previous
//
#include <hip/hip_runtime.h>
#include <hip/hip_bf16.h>
#include <math.h>

#define BB 8
#define CC 128
#define NTOK 2304   // 48*48
#define KTOP 1843   // int(2304*0.8)

typedef unsigned short u16;
typedef unsigned int   u32;
typedef __attribute__((ext_vector_type(8))) short short8;
typedef __attribute__((ext_vector_type(4))) float f32x4;

static __device__ __forceinline__ float bf2f(u16 u) {
    return __uint_as_float(((u32)u) << 16);
}
static __device__ __forceinline__ u16 f2bf(float f) {
    u32 x = __float_as_uint(f);
    return (u16)((x + 0x7fffu + ((x >> 16) & 1u)) >> 16);  // RNE
}
// monotone 16-bit key <-> bf16 value
static __device__ __forceinline__ float key2val(int k) {
    u32 raw = (k & 0x8000) ? (u32)(k ^ 0x8000) : ((~(u32)k) & 0xFFFFu);
    return __uint_as_float(raw << 16);
}

// ---------------- Kernel 1: QKV projections (bf16 outputs) ----------------
// Q,K: [B,N,C] bf16 (Q pre-scaled by 1/sqrt(C)); V: [B,C,N] bf16 (transposed).
__global__ __launch_bounds__(256) void qkv_kernel(
    const float* __restrict__ x,
    const float* __restrict__ Wq, const float* __restrict__ bq,
    const float* __restrict__ Wk, const float* __restrict__ bk,
    const float* __restrict__ Wv, const float* __restrict__ bv,
    u16* __restrict__ q_ws, u16* __restrict__ k_ws, u16* __restrict__ v_ws)
{
    __shared__ float t_lds[128 * 68];   // [c][r]
    __shared__ u16 st[64 * 128];        // transpose staging for q/k stores
    int blk = blockIdx.x;
    int b  = blk / 36;
    int n0 = (blk % 36) * 64;
    int tid = threadIdx.x;
    const float* xb = x + (size_t)(b * NTOK + n0) * CC;
    #pragma unroll
    for (int k = 0; k < 32; ++k) {
        int idx = k * 256 + tid;
        t_lds[(idx & 127) * 68 + (idx >> 7)] = xb[idx];
    }
    __syncthreads();
    int o  = tid & 127;
    int rh = tid >> 7;
    const float* Ws[3] = {Wq, Wk, Wv};
    const float* bs[3] = {bq, bk, bv};
    for (int mat = 0; mat < 3; ++mat) {
        const float* W = Ws[mat];
        float acc[32];
        #pragma unroll
        for (int j = 0; j < 32; ++j) acc[j] = 0.f;
        for (int c = 0; c < 128; ++c) {
            float w = W[o * 128 + c];
            const float4* t4p = (const float4*)&t_lds[c * 68 + rh * 32];
            #pragma unroll
            for (int j4 = 0; j4 < 8; ++j4) {
                float4 t4 = t4p[j4];
                acc[j4*4+0] += t4.x * w;
                acc[j4*4+1] += t4.y * w;
                acc[j4*4+2] += t4.z * w;
                acc[j4*4+3] += t4.w * w;
            }
        }
        float bias = bs[mat][o];
        if (mat == 2) {
            ushort4* vp4 = (ushort4*)(v_ws + (size_t)(b * CC + o) * NTOK + n0 + rh * 32);
            #pragma unroll
            for (int j8 = 0; j8 < 8; ++j8) {
                ushort4 s;
                s.x = f2bf(acc[j8*4+0] + bias); s.y = f2bf(acc[j8*4+1] + bias);
                s.z = f2bf(acc[j8*4+2] + bias); s.w = f2bf(acc[j8*4+3] + bias);
                vp4[j8] = s;
            }
        } else {
            float sc = (mat == 0) ? 0.08838834764831845f : 1.0f;  // fold 1/sqrt(C) into Q
            #pragma unroll
            for (int j = 0; j < 32; ++j)
                st[(rh * 32 + j) * 128 + o] = f2bf((acc[j] + bias) * sc);
            __syncthreads();
            u16* gp = (mat == 0 ? q_ws : k_ws) + (size_t)(b * NTOK + n0) * CC;
            const ushort4* s4 = (const ushort4*)st;
            ushort4* g4 = (ushort4*)gp;
            for (int k = tid; k < 2048; k += 256) g4[k] = s4[k];
            __syncthreads();
        }
    }
}

// ---------------- Kernel 2a: QK^T GEMM -> monotone u16 keys [B][N][N] ------
// Block: 64 q-rows x 64 m-cols, 4 waves (wave = 16q x 64m), no LDS.
__global__ __launch_bounds__(256) void qk_kernel(
    const u16* __restrict__ q_ws, const u16* __restrict__ k_ws,
    u16* __restrict__ sc)
{
    int tid = threadIdx.x;
    int lane = tid & 63, wid = tid >> 6;
    int blk = blockIdx.x;
    int b = blk & 7;                // one batch per XCD (Q,K L2-resident)
    int t = blk >> 3;               // 0..1295
    int qt = t % 36, mt = t / 36;
    int q0 = qt * 64 + wid * 16;
    int m0 = mt * 64;
    int fr = lane & 15, fg = lane >> 4;

    const u16* qb = q_ws + (size_t)(b * NTOK + q0 + fr) * CC + fg * 8;
    short8 qa[4];
    #pragma unroll
    for (int kc = 0; kc < 4; ++kc) qa[kc] = *(const short8*)(qb + kc * 32);

    const u16* kb = k_ws + (size_t)(b * NTOK + m0 + fr) * CC + fg * 8;
    f32x4 acc[4];
    #pragma unroll
    for (int i = 0; i < 4; ++i) acc[i] = (f32x4){0.f, 0.f, 0.f, 0.f};
    #pragma unroll
    for (int mt2 = 0; mt2 < 4; ++mt2) {
        const u16* kp = kb + (size_t)(mt2 * 16) * CC;
        #pragma unroll
        for (int kc = 0; kc < 4; ++kc) {
            short8 kf = *(const short8*)(kp + kc * 32);
            acc[mt2] = __builtin_amdgcn_mfma_f32_16x16x32_bf16(qa[kc], kf, acc[mt2], 0, 0, 0);
        }
    }
    #pragma unroll
    for (int mt2 = 0; mt2 < 4; ++mt2) {
        #pragma unroll
        for (int r = 0; r < 4; ++r) {
            int row = q0 + fg * 4 + r;
            int col = m0 + mt2 * 16 + fr;
            u16 raw = f2bf(acc[mt2][r]);
            u16 key = (raw & 0x8000u) ? (u16)~raw : (u16)(raw | 0x8000u);
            sc[((size_t)b * NTOK + row) * NTOK + col] = key;
        }
    }
}

// ---------------- Kernel 2b: exact top-k + masked softmax (writes P) -------
// Block = 4 waves x 2 fused rows = 8 rows; keys in registers; no LDS/barriers.
// Writes P (bf16) in place over keys; params[row].z = 1/sum for pv epilogue.
__global__ __launch_bounds__(256) void topk_kernel(
    u16* __restrict__ sc, float4* __restrict__ params)
{
    int tid = threadIdx.x;
    int lane = tid & 63, wid = tid >> 6;
    size_t rg0 = (size_t)blockIdx.x * 8 + wid * 2;
    u16* s0 = sc + rg0 * NTOK;
    u16* s1 = s0 + NTOK;

    int keys0[36], keys1[36];
    int kmax0 = 0, kmax1 = 0;
    #pragma unroll
    for (int j = 0; j < 9; ++j) {
        ushort4 a = *(const ushort4*)(s0 + j * 256 + lane * 4);
        ushort4 c = *(const ushort4*)(s1 + j * 256 + lane * 4);
        keys0[j*4+0] = a.x; keys0[j*4+1] = a.y; keys0[j*4+2] = a.z; keys0[j*4+3] = a.w;
        keys1[j*4+0] = c.x; keys1[j*4+1] = c.y; keys1[j*4+2] = c.z; keys1[j*4+3] = c.w;
        kmax0 = max(kmax0, max(max((int)a.x, (int)a.y), max((int)a.z, (int)a.w)));
        kmax1 = max(kmax1, max(max((int)c.x, (int)c.y), max((int)c.z, (int)c.w)));
    }
    #pragma unroll
    for (int off = 32; off; off >>= 1) {
        kmax0 = max(kmax0, __shfl_xor(kmax0, off, 64));
        kmax1 = max(kmax1, __shfl_xor(kmax1, off, 64));
    }
    u32 res0 = 0, res1 = 0;
    for (int bit = 15; bit >= 0; --bit) {
        int cand0 = (int)(res0 | (1u << bit));
        int cand1 = (int)(res1 | (1u << bit));
        int c0 = 0, c1 = 0;
        #pragma unroll
        for (int j = 0; j < 36; ++j) {
            c0 += (keys0[j] >= cand0) ? 1 : 0;
            c1 += (keys1[j] >= cand1) ? 1 : 0;
        }
        #pragma unroll
        for (int off = 32; off; off >>= 1) {
            c0 += __shfl_xor(c0, off, 64);
            c1 += __shfl_xor(c1, off, 64);
        }
        if (c0 >= KTOP) res0 = (u32)cand0;
        if (c1 >= KTOP) res1 = (u32)cand1;
    }
    float vmax0 = key2val(kmax0), vmax1 = key2val(kmax1);
    float sum0 = 0.f, sum1 = 0.f;
    #pragma unroll
    for (int j = 0; j < 9; ++j) {
        ushort4 w0, w1;
        float e;
        e = ((u32)keys0[j*4+0] >= res0) ? __expf(key2val(keys0[j*4+0]) - vmax0) : 0.f; sum0 += e; w0.x = f2bf(e);
        e = ((u32)keys0[j*4+1] >= res0) ? __expf(key2val(keys0[j*4+1]) - vmax0) : 0.f; sum0 += e; w0.y = f2bf(e);
        e = ((u32)keys0[j*4+2] >= res0) ? __expf(key2val(keys0[j*4+2]) - vmax0) : 0.f; sum0 += e; w0.z = f2bf(e);
        e = ((u32)keys0[j*4+3] >= res0) ? __expf(key2val(keys0[j*4+3]) - vmax0) : 0.f; sum0 += e; w0.w = f2bf(e);
        e = ((u32)keys1[j*4+0] >= res1) ? __expf(key2val(keys1[j*4+0]) - vmax1) : 0.f; sum1 += e; w1.x = f2bf(e);
        e = ((u32)keys1[j*4+1] >= res1) ? __expf(key2val(keys1[j*4+1]) - vmax1) : 0.f; sum1 += e; w1.y = f2bf(e);
        e = ((u32)keys1[j*4+2] >= res1) ? __expf(key2val(keys1[j*4+2]) - vmax1) : 0.f; sum1 += e; w1.z = f2bf(e);
        e = ((u32)keys1[j*4+3] >= res1) ? __expf(key2val(keys1[j*4+3]) - vmax1) : 0.f; sum1 += e; w1.w = f2bf(e);
        *(ushort4*)(s0 + j * 256 + lane * 4) = w0;
        *(ushort4*)(s1 + j * 256 + lane * 4) = w1;
    }
    #pragma unroll
    for (int off = 32; off; off >>= 1) {
        sum0 += __shfl_xor(sum0, off, 64);
        sum1 += __shfl_xor(sum1, off, 64);
    }
    if (lane == 0) {
        params[rg0]     = make_float4(0.f, vmax0, 1.f / sum0, 0.f);
        params[rg0 + 1] = make_float4(0.f, vmax1, 1.f / sum1, 0.f);
    }
}

// ---------------- Kernel 2c: PV GEMM, m-split + LDS block reduction --------
// Block = 4 waves x 16 rows; wave w owns m in [w*576, w*576+576) for ALL 128 c
// (9 independent loads + 8 MFMAs per 32-m chunk -> deep load window, P read
// once per chip). Partials reduced across waves via padded LDS.
__global__ __launch_bounds__(256) void pv_kernel(
    const u16* __restrict__ sc, const u16* __restrict__ v_ws,
    const float4* __restrict__ params, float* __restrict__ xs_ws)
{
    __shared__ float red[4 * 16 * 130];   // [wave][row][c], pad 130 vs 128
    int tid = threadIdx.x;
    int lane = tid & 63, wid = tid >> 6;
    int blk = blockIdx.x;
    int b = blk & 7;                 // one batch per XCD (V L2-resident)
    int rt = blk >> 3;               // 0..143
    int r0 = rt * 16;
    int fr = lane & 15, fg = lane >> 4;
    int row = r0 + fr;
    int mbase = wid * 576;

    const u16* pb = sc + ((size_t)b * NTOK + row) * NTOK + mbase + fg * 8;
    const u16* vb = v_ws + ((size_t)b * CC + fr) * NTOK + mbase + fg * 8;

    f32x4 acc[8];
    #pragma unroll
    for (int i = 0; i < 8; ++i) acc[i] = (f32x4){0.f, 0.f, 0.f, 0.f};

    #pragma unroll 2
    for (int ch = 0; ch < 18; ++ch) {
        int m0 = ch * 32;
        short8 pa = *(const short8*)(pb + m0);
        short8 vf0 = *(const short8*)(vb + (size_t)(0 * 16) * NTOK + m0);
        short8 vf1 = *(const short8*)(vb + (size_t)(1 * 16) * NTOK + m0);
        short8 vf2 = *(const short8*)(vb + (size_t)(2 * 16) * NTOK + m0);
        short8 vf3 = *(const short8*)(vb + (size_t)(3 * 16) * NTOK + m0);
        short8 vf4 = *(const short8*)(vb + (size_t)(4 * 16) * NTOK + m0);
        short8 vf5 = *(const short8*)(vb + (size_t)(5 * 16) * NTOK + m0);
        short8 vf6 = *(const short8*)(vb + (size_t)(6 * 16) * NTOK + m0);
        short8 vf7 = *(const short8*)(vb + (size_t)(7 * 16) * NTOK + m0);
        acc[0] = __builtin_amdgcn_mfma_f32_16x16x32_bf16(pa, vf0, acc[0], 0, 0, 0);
        acc[1] = __builtin_amdgcn_mfma_f32_16x16x32_bf16(pa, vf1, acc[1], 0, 0, 0);
        acc[2] = __builtin_amdgcn_mfma_f32_16x16x32_bf16(pa, vf2, acc[2], 0, 0, 0);
        acc[3] = __builtin_amdgcn_mfma_f32_16x16x32_bf16(pa, vf3, acc[3], 0, 0, 0);
        acc[4] = __builtin_amdgcn_mfma_f32_16x16x32_bf16(pa, vf4, acc[4], 0, 0, 0);
        acc[5] = __builtin_amdgcn_mfma_f32_16x16x32_bf16(pa, vf5, acc[5], 0, 0, 0);
        acc[6] = __builtin_amdgcn_mfma_f32_16x16x32_bf16(pa, vf6, acc[6], 0, 0, 0);
        acc[7] = __builtin_amdgcn_mfma_f32_16x16x32_bf16(pa, vf7, acc[7], 0, 0, 0);
    }
    // write partials: row_m = fg*4+r, c = t*16+fr; pad 130 decorrelates banks
    float* myred = red + wid * (16 * 130);
    #pragma unroll
    for (int t = 0; t < 8; ++t)
        #pragma unroll
        for (int r = 0; r < 4; ++r)
            myred[(fg * 4 + r) * 130 + t * 16 + fr] = acc[t][r];
    __syncthreads();
    // reduce 4 waves' partials; coalesced fp32 stores
    #pragma unroll
    for (int k = 0; k < 8; ++k) {
        int idx = k * 256 + tid;          // 0..2047
        int rr = idx >> 7, c = idx & 127;
        int loff = rr * 130 + c;
        float s = red[loff] + red[16 * 130 + loff]
                + red[2 * 16 * 130 + loff] + red[3 * 16 * 130 + loff];
        float inv = params[(size_t)b * NTOK + r0 + rr].z;
        xs_ws[((size_t)b * NTOK + r0 + rr) * CC + c] = s * inv;
    }
}

// ---------------- Kernel 3: gate conv + sigmoid ----------------------------
__global__ __launch_bounds__(256) void gate_kernel(
    const float* __restrict__ xs_ws, const float* __restrict__ gw,
    const float* __restrict__ gb, float* __restrict__ imp_ws)
{
    __shared__ float gsum[256];
    int blk = blockIdx.x;
    int b  = blk & 7;
    int p0 = (blk >> 3) * 64;
    int tid = threadIdx.x;
    int pl = tid & 63, cq = tid >> 6;
    int p = p0 + pl;
    int h = p / 48, w = p % 48;
    float acc = 0.f;
    const float* xb = xs_ws + (size_t)b * CC * NTOK;
    for (int i = cq * 32; i < cq * 32 + 32; ++i) {
        const float* plane = xb + (size_t)i * NTOK;
        const float* wv = gw + i * 9;
        #pragma unroll
        for (int kh = 0; kh < 3; ++kh) {
            int hh = h + kh - 1;
            if ((unsigned)hh >= 48u) continue;
            #pragma unroll
            for (int kw = 0; kw < 3; ++kw) {
                int ww = w + kw - 1;
                if ((unsigned)ww >= 48u) continue;
                acc += plane[hh * 48 + ww] * wv[kh * 3 + kw];
            }
        }
    }
    gsum[cq * 64 + pl] = acc;
    __syncthreads();
    if (tid < 64) {
        float s = gsum[tid] + gsum[64 + tid] + gsum[128 + tid] + gsum[192 + tid] + gb[0];
        imp_ws[b * NTOK + p0 + tid] = 1.f / (1.f + __expf(-s));
    }
}

// ---------------- Kernel 3b: weight transform -> wb[tap][o][c] bf16 --------
__global__ __launch_bounds__(256) void wtrans_kernel(
    const float* __restrict__ rw, const float* __restrict__ cw,
    u16* __restrict__ wb_ref, u16* __restrict__ wb_cov)
{
    int idx = blockIdx.x * 256 + threadIdx.x;     // 0..294911
    int which = idx >= 147456;
    int rem = which ? idx - 147456 : idx;
    int tap = rem >> 14;                           // /16384
    int rest = rem & 16383;
    int o = rest >> 7, c = rest & 127;
    const float* src = which ? cw : rw;
    u16* dst = which ? wb_cov : wb_ref;
    dst[rem] = f2bf(src[(o * 128 + c) * 9 + tap]);
}

// ---------------- Kernel 3c: transpose to pixel-major + residual buffer ----
__global__ __launch_bounds__(256) void tpos_kernel(
    const float* __restrict__ xs_ws, const float* __restrict__ prev,
    const float* __restrict__ imp_ws,
    u16* __restrict__ xt_g, float* __restrict__ rbuf)
{
    __shared__ float tx[128 * 65];
    __shared__ float tp[128 * 65];
    int blk = blockIdx.x;
    int b  = blk & 7;
    int p0 = (blk >> 3) * 64;
    int tid = threadIdx.x;
    const float* xsb = xs_ws + (size_t)b * CC * NTOK + p0;
    const float* pvb = prev  + (size_t)b * CC * NTOK + p0;
    #pragma unroll
    for (int it = 0; it < 32; ++it) {
        int idx = it * 256 + tid;
        int i = idx >> 6, pp = idx & 63;
        tx[i * 65 + pp] = xsb[(size_t)i * NTOK + pp];
        tp[i * 65 + pp] = pvb[(size_t)i * NTOK + pp];
    }
    __syncthreads();
    int pl = tid & 63, cq = tid >> 6;
    float impv = imp_ws[b * NTOK + p0 + pl];
    size_t obase = ((size_t)b * NTOK + p0 + pl) * CC + cq * 32;
    u16* gout = xt_g + obase;
    float* rout = rbuf + obase;
    #pragma unroll
    for (int j4 = 0; j4 < 8; ++j4) {
        float4 rv; ushort4 gv;
        float v0 = tx[(cq * 32 + j4 * 4 + 0) * 65 + pl];
        float v1 = tx[(cq * 32 + j4 * 4 + 1) * 65 + pl];
        float v2 = tx[(cq * 32 + j4 * 4 + 2) * 65 + pl];
        float v3 = tx[(cq * 32 + j4 * 4 + 3) * 65 + pl];
        float q0 = tp[(cq * 32 + j4 * 4 + 0) * 65 + pl];
        float q1 = tp[(cq * 32 + j4 * 4 + 1) * 65 + pl];
        float q2 = tp[(cq * 32 + j4 * 4 + 2) * 65 + pl];
        float q3 = tp[(cq * 32 + j4 * 4 + 3) * 65 + pl];
        rv.x = v0 + 0.5f * q0; rv.y = v1 + 0.5f * q1;
        rv.z = v2 + 0.5f * q2; rv.w = v3 + 0.5f * q3;
        gv.x = f2bf(v0 * impv); gv.y = f2bf(v1 * impv);
        gv.z = f2bf(v2 * impv); gv.w = f2bf(v3 * impv);
        *(float4*)(rout + j4 * 4) = rv;
        *(ushort4*)(gout + j4 * 4) = gv;
    }
}

// ---------------- Kernel 4: refinement conv as implicit MFMA GEMM ----------
__global__ __launch_bounds__(256) void refgemm_kernel(
    const u16* __restrict__ xt_g, const u16* __restrict__ wb_ref,
    const float* __restrict__ rbuf, const float* __restrict__ rb,
    u16* __restrict__ xt2)
{
    __shared__ u16 slab[144 * 128];   // XOR-swizzled shifted input slab
    int tid = threadIdx.x;
    int lane = tid & 63, wid = tid >> 6;
    int blk = blockIdx.x;
    int b  = blk & 7;
    int st = (blk >> 3) & 15;
    int oh = blk >> 7;
    int h0 = st * 3;
    int p0g = st * 144;
    int fr = lane & 15, fg = lane >> 4;
    int o0 = oh * 64 + wid * 16;
    const u16* xb = xt_g + (size_t)b * NTOK * CC;

    f32x4 acc[9];
    #pragma unroll
    for (int pt = 0; pt < 9; ++pt) acc[pt] = (f32x4){0.f, 0.f, 0.f, 0.f};

    for (int tap = 0; tap < 9; ++tap) {
        int dh = tap / 3 - 1, dw = tap % 3 - 1;
        __syncthreads();
        #pragma unroll
        for (int it = 0; it < 9; ++it) {
            int idx = it * 256 + tid;          // 0..2303
            int pr = idx >> 4, cv = idx & 15;
            int r = pr >= 96 ? 2 : (pr >= 48 ? 1 : 0);
            int w = pr - r * 48;
            int sh = h0 + r + dh, sw = w + dw;
            short8 val = (short8){0,0,0,0,0,0,0,0};
            if ((unsigned)sh < 48u && (unsigned)sw < 48u)
                val = *(const short8*)(xb + (size_t)(sh * 48 + sw) * CC + cv * 8);
            *(short8*)(slab + pr * 128 + ((cv ^ (pr & 7)) * 8)) = val;
        }
        __syncthreads();
        #pragma unroll
        for (int kc = 0; kc < 4; ++kc) {
            short8 bfr = *(const short8*)(wb_ref + tap * 16384 + (o0 + fr) * 128 + kc * 32 + fg * 8);
            #pragma unroll
            for (int pt = 0; pt < 9; ++pt) {
                int prr = pt * 16 + fr;
                short8 pa = *(const short8*)(slab + prr * 128 + (((kc * 4 + fg) ^ (prr & 7)) * 8));
                acc[pt] = __builtin_amdgcn_mfma_f32_16x16x32_bf16(pa, bfr, acc[pt], 0, 0, 0);
            }
        }
    }
    int o = o0 + fr;
    float bias = rb[o];
    #pragma unroll
    for (int pt = 0; pt < 9; ++pt) {
        #pragma unroll
        for (int r = 0; r < 4; ++r) {
            int p = p0g + pt * 16 + fg * 4 + r;
            size_t off = ((size_t)b * NTOK + p) * CC + o;
            float v = acc[pt][r] + bias + rbuf[off];
            xt2[off] = f2bf(v);
        }
    }
}

// ---------------- Kernel 5: coverage conv (dil 2) as implicit MFMA GEMM ----
__global__ __launch_bounds__(256) void covgemm_kernel(
    const u16* __restrict__ xt2, const u16* __restrict__ wb_cov,
    const float* __restrict__ cb, float* __restrict__ out)
{
    __shared__ u16 slab[144 * 128];
    __shared__ float ldsout[4 * 16 * 145];   // per-wave [o][p] staging, padded
    int tid = threadIdx.x;
    int lane = tid & 63, wid = tid >> 6;
    int blk = blockIdx.x;
    int b  = blk & 7;
    int st = (blk >> 3) & 15;
    int oh = blk >> 7;
    int h0 = st * 3;
    int p0g = st * 144;
    int fr = lane & 15, fg = lane >> 4;
    int o0 = oh * 64 + wid * 16;
    const u16* xb = xt2 + (size_t)b * NTOK * CC;

    f32x4 acc[9];
    #pragma unroll
    for (int pt = 0; pt < 9; ++pt) acc[pt] = (f32x4){0.f, 0.f, 0.f, 0.f};

    for (int tap = 0; tap < 9; ++tap) {
        int dh = (tap / 3 - 1) * 2, dw = (tap % 3 - 1) * 2;
        __syncthreads();
        #pragma unroll
        for (int it = 0; it < 9; ++it) {
            int idx = it * 256 + tid;
            int pr = idx >> 4, cv = idx & 15;
            int r = pr >= 96 ? 2 : (pr >= 48 ? 1 : 0);
            int w = pr - r * 48;
            int sh = h0 + r + dh, sw = w + dw;
            short8 val = (short8){0,0,0,0,0,0,0,0};
            if ((unsigned)sh < 48u && (unsigned)sw < 48u)
                val = *(const short8*)(xb + (size_t)(sh * 48 + sw) * CC + cv * 8);
            *(short8*)(slab + pr * 128 + ((cv ^ (pr & 7)) * 8)) = val;
        }
        __syncthreads();
        #pragma unroll
        for (int kc = 0; kc < 4; ++kc) {
            short8 bfr = *(const short8*)(wb_cov + tap * 16384 + (o0 + fr) * 128 + kc * 32 + fg * 8);
            #pragma unroll
            for (int pt = 0; pt < 9; ++pt) {
                int prr = pt * 16 + fr;
                short8 pa = *(const short8*)(slab + prr * 128 + (((kc * 4 + fg) ^ (prr & 7)) * 8));
                acc[pt] = __builtin_amdgcn_mfma_f32_16x16x32_bf16(pa, bfr, acc[pt], 0, 0, 0);
            }
        }
    }
    float bias = cb[o0 + fr];
    float* lo = ldsout + wid * (16 * 145);
    #pragma unroll
    for (int pt = 0; pt < 9; ++pt) {
        #pragma unroll
        for (int r = 0; r < 4; ++r) {
            int pl = pt * 16 + fg * 4 + r;
            lo[fr * 145 + pl] = acc[pt][r] + bias;
        }
    }
    __syncthreads();
    float* ob = out + ((size_t)b * CC + o0) * NTOK + p0g;
    #pragma unroll
    for (int j = 0; j < 36; ++j) {
        int idx = j * 64 + lane;         // 0..2303
        int o_r = idx / 144;
        int p_r = idx - o_r * 144;
        ob[(size_t)o_r * NTOK + p_r] = lo[o_r * 145 + p_r];
    }
}

extern "C" void kernel_launch(void* const* d_in, const int* in_sizes, int n_in,
                              void* d_out, int out_size, void* d_ws, size_t ws_size,
                              hipStream_t stream)
{
    const float* x    = (const float*)d_in[0];
    const float* prev = (const float*)d_in[1];
    const float* Wq   = (const float*)d_in[2];
    const float* bq   = (const float*)d_in[3];
    const float* Wk   = (const float*)d_in[4];
    const float* bk   = (const float*)d_in[5];
    const float* Wv   = (const float*)d_in[6];
    const float* bv   = (const float*)d_in[7];
    const float* rw   = (const float*)d_in[8];
    const float* rb   = (const float*)d_in[9];
    const float* gw   = (const float*)d_in[10];
    const float* gb   = (const float*)d_in[11];
    const float* cw   = (const float*)d_in[12];
    const float* cb   = (const float*)d_in[13];
    float* out = (float*)d_out;
    char* ws = (char*)d_ws;

    const size_t SZ  = (size_t)BB * NTOK * CC;            // 2359296 elements
    const size_t BSZ = SZ * 2;                            // bf16 bytes
    const size_t FSZ = SZ * 4;                            // fp32 bytes
    const size_t SCB = (size_t)BB * NTOK * NTOK * 2;      // 84.9 MB key/P buffer
    const size_t PRB = (size_t)BB * NTOK * 16;            // params float4/row
    const size_t RIB = (size_t)BB * NTOK * 4;

    size_t off = 0;
    u16*    q_ws   = (u16*)(ws + off);    off += BSZ;
    u16*    k_ws   = (u16*)(ws + off);    off += BSZ;
    u16*    v_ws   = (u16*)(ws + off);    off += BSZ;
    u16*    sc_ws  = (u16*)(ws + off);    off += SCB;
    float4* prm_ws = (float4*)(ws + off); off += PRB;
    float*  xs_ws  = (float*)(ws + off);  off += FSZ;
    float*  imp_ws = (float*)(ws + off);  off += RIB;
    u16*    xt_g   = (u16*)(ws + off);    off += BSZ;
    float*  rbuf   = (float*)(ws + off);  off += FSZ;
    u16*    xt2    = (u16*)(ws + off);    off += BSZ;
    u16*    wb_ref = (u16*)(ws + off);    off += 294912;
    u16*    wb_cov = (u16*)(ws + off);    off += 294912;
    // total ~124 MB

    qkv_kernel<<<dim3(288), dim3(256), 0, stream>>>(x, Wq, bq, Wk, bk, Wv, bv,
                                                    q_ws, k_ws, v_ws);
    qk_kernel<<<dim3(10368), dim3(256), 0, stream>>>(q_ws, k_ws, sc_ws);
    topk_kernel<<<dim3(2304), dim3(256), 0, stream>>>(sc_ws, prm_ws);
    pv_kernel<<<dim3(1152), dim3(256), 0, stream>>>(sc_ws, v_ws, prm_ws, xs_ws);
    gate_kernel<<<dim3(288), dim3(256), 0, stream>>>(xs_ws, gw, gb, imp_ws);
    wtrans_kernel<<<dim3(1152), dim3(256), 0, stream>>>(rw, cw, wb_ref, wb_cov);
    tpos_kernel<<<dim3(288), dim3(256), 0, stream>>>(xs_ws, prev, imp_ws, xt_g, rbuf);
    refgemm_kernel<<<dim3(256), dim3(256), 0, stream>>>(xt_g, wb_ref, rbuf, rb, xt2);
    covgemm_kernel<<<dim3(256), dim3(256), 0, stream>>>(xt2, wb_cov, cb, out);
}